// Round 9
// baseline (169.952 us; speedup 1.0000x reference)
//
#include <hip/hip_runtime.h>
#include <math.h>

typedef _Float16 f16;
typedef f16   f16x8    __attribute__((ext_vector_type(8)));
typedef float floatx2  __attribute__((ext_vector_type(2)));
typedef float floatx4  __attribute__((ext_vector_type(4)));
typedef float floatx16 __attribute__((ext_vector_type(16)));

#define LOG2E 1.44269504088896340736f
#define LN2   0.69314718055994530942f

// Problem constants
#define B_SZ  2048
#define DIN   64
#define DOUT  64
#define NH    32

#define NIG   4                 // i-groups: 8192 blocks
#define IGW   (DIN / NIG)       // 16 i per block

// Images:
//  w1img f16 [i][o][lane(64)][j(8)]: A-frag mfma_32x32x16, m=h=lane&31,
//        k=(lane>>5)*8+j; lanes 32..63 ZERO. Scaled by -log2e; j==7 = B1*(-log2e).
//  fimg  f16 [i][btp(64)][lane(64)][j(8)]: B-frag, n=b=lane&31; j==7 = 1.0.
//        lanes 32..63 never consumed (A zero there) -> not written.
//  W2 read RAW in main ([i][o][h] natively serves the C-layout float4 gather);
//  the -ln2 factor applied once per wave at the end.
#define W1IMG_ELEMS ((size_t)DIN * DOUT * 64 * 8)   // 4 MB
#define FIMG_ELEMS  ((size_t)DIN * 64 * 64 * 8)     // 4 MB

// ---------------------------------------------------------------------------
// prep: bid [0,256)   w1img — 16 (i,o) pairs/block via LDS (coalesced)
//       bid [256,320) fimg  — 1 btp/block, coalesced x via LDS transpose
//       bid [320,832) out[b,o] = sum_i B2[i,o]  (main atomically accumulates)
// ---------------------------------------------------------------------------
__global__ __launch_bounds__(256) void prep_kernel(
        const float* __restrict__ W1, const float* __restrict__ B1,
        const float* __restrict__ B2, const float* __restrict__ x,
        f16* __restrict__ w1img, f16* __restrict__ fimg,
        float* __restrict__ out) {
    const int bid = blockIdx.x, tid = threadIdx.x;
    if (bid < 256) {
        __shared__ float l1[16 * 225];
        __shared__ float lb[16 * 32];
        const int base = bid * 16;       // pair = i*64+o
        for (int g = tid; g < 3584; g += 256) {
            int pair = g / 224, r = g % 224;
            l1[pair * 225 + r] = W1[(size_t)base * 224 + g];
        }
        for (int g = tid; g < 512; g += 256) lb[g] = B1[(size_t)base * 32 + g];
        __syncthreads();
        for (int g = tid; g < 1024; g += 256) {
            int pair = g >> 6, lane = g & 63;
            f16x8 v = {};
            if (lane < 32) {
#pragma unroll
                for (int j = 0; j < 7; ++j)
                    v[j] = (f16)(l1[pair * 225 + lane * 7 + j] * (-LOG2E));
                v[7] = (f16)(lb[pair * 32 + lane] * (-LOG2E));
            }
            *(f16x8*)(w1img + (size_t)bid * 8192 + (size_t)g * 8) = v;
        }
    } else if (bid < 320) {
        __shared__ float ls[32 * 65];
        const int btp = bid - 256;
        for (int g = tid; g < 2048; g += 256) {
            int bb = g >> 6, i = g & 63;
            ls[bb * 65 + i] = x[(size_t)(btp * 32 + bb) * 64 + i];
        }
        __syncthreads();
        for (int g = tid; g < 2048; g += 256) {
            int bb = g & 31, i = g >> 5;
            float xv = ls[bb * 65 + i];
            float s1, c1;
            __sincosf(xv, &s1, &c1);
            float s2 = 2.0f * s1 * c1, c2 = 1.0f - 2.0f * s1 * s1;
            float s4 = 2.0f * s2 * c2, c4 = 1.0f - 2.0f * s2 * s2;
            f16x8 v;
            v[0] = (f16)xv; v[1] = (f16)s1; v[2] = (f16)s2; v[3] = (f16)s4;
            v[4] = (f16)c1; v[5] = (f16)c2; v[6] = (f16)c4; v[7] = (f16)1.0f;
            *(f16x8*)(fimg + ((size_t)(i * 64 + btp) * 64 + bb) * 8) = v;
        }
    } else {
        int e = (bid - 320) * 256 + tid;  // < 131072
        int o = e & 63;
        float s = 0.0f;
#pragma unroll 8
        for (int i = 0; i < 64; ++i) s += B2[i * 64 + o];
        out[e] = s;
    }
}

// ---------------------------------------------------------------------------
// main: grid = 4 ig x 32 og x 64 btp = 8192 blocks, block 128 (2 waves);
// wave w -> o = og*2+w; 16 i/block. Two-stage pipeline: the MFMA for the
// NEXT i is issued before the silu of the current C, and a/b fragments are
// loaded one half-iteration ahead. silu add/mul/fma written as float2 ops
// to let the backend form v_pk_*_f32 (halves full-rate issue count).
// Tail over-reads land in mapped ws (finite garbage, never accumulated).
// ---------------------------------------------------------------------------
__device__ __forceinline__ void silu_reduce(const floatx16& C,
                                            const float* __restrict__ wb,
                                            floatx2& phi) {
#pragma unroll
    for (int q = 0; q < 4; ++q) {
        const floatx4 w = *(const floatx4*)(wb + q * 8);
        floatx2 t0 = { C[4 * q + 0], C[4 * q + 1] };
        floatx2 t1 = { C[4 * q + 2], C[4 * q + 3] };
        floatx2 u0 = { __builtin_amdgcn_exp2f(t0.x), __builtin_amdgcn_exp2f(t0.y) };
        floatx2 u1 = { __builtin_amdgcn_exp2f(t1.x), __builtin_amdgcn_exp2f(t1.y) };
        floatx2 v0 = u0 + (floatx2){1.0f, 1.0f};      // v_pk_add_f32
        floatx2 v1 = u1 + (floatx2){1.0f, 1.0f};
        floatx2 p0 = t0 * (floatx2){w[0], w[1]};      // v_pk_mul_f32
        floatx2 p1 = t1 * (floatx2){w[2], w[3]};
        floatx2 s0 = { __builtin_amdgcn_rcpf(v0.x), __builtin_amdgcn_rcpf(v0.y) };
        floatx2 s1 = { __builtin_amdgcn_rcpf(v1.x), __builtin_amdgcn_rcpf(v1.y) };
        phi = __builtin_elementwise_fma(p0, s0, phi); // v_pk_fma_f32
        phi = __builtin_elementwise_fma(p1, s1, phi);
    }
}

__global__ __launch_bounds__(128, 6) void main_kernel(
        const f16* __restrict__ w1img, const f16* __restrict__ fimg,
        const float* __restrict__ W2, float* __restrict__ out) {
    const int tid  = threadIdx.x;
    const int lane = tid & 63;
    const int wv   = tid >> 6;
    const int btp  = blockIdx.x & 63;
    const int og   = (blockIdx.x >> 6) & 31;
    const int ig   = blockIdx.x >> 11;
    const int o    = __builtin_amdgcn_readfirstlane(og * 2 + wv);
    const int p    = lane >> 5;

    const size_t ibase = (size_t)ig * IGW;
    const f16*   ap = w1img + ibase * 32768 + ((size_t)o * 64 + lane) * 8;
    const f16*   bp = fimg  + ibase * 32768 + ((size_t)btp * 64 + lane) * 8;
    const float* wp = W2    + ibase * 2048  + (size_t)o * 32 + p * 4;

    const floatx16 zeroC = {};
    floatx2 phi = {0.0f, 0.0f};

    // prologue: even chain (ii=0) and odd chain (ii=1)
    f16x8 aE = *(const f16x8*)(ap);
    f16x8 bE = *(const f16x8*)(bp);
    f16x8 aO = *(const f16x8*)(ap + 32768);
    f16x8 bO = *(const f16x8*)(bp + 32768);
    floatx16 C0 = __builtin_amdgcn_mfma_f32_32x32x16_f16(aE, bE, zeroC, 0, 0, 0);
    aE = *(const f16x8*)(ap + 2 * 32768);
    bE = *(const f16x8*)(bp + 2 * 32768);

#pragma unroll 1
    for (int kk = 0; kk < 8; ++kk) {
        const size_t i0 = (size_t)(2 * kk);

        // odd MFMA (ii = 2kk+1) issued before even silu
        floatx16 C1 = __builtin_amdgcn_mfma_f32_32x32x16_f16(aO, bO, zeroC, 0, 0, 0);
        aO = *(const f16x8*)(ap + (i0 + 3) * 32768);   // prefetch ii+3
        bO = *(const f16x8*)(bp + (i0 + 3) * 32768);

        silu_reduce(C0, wp + i0 * 2048, phi);

        // even MFMA (ii = 2kk+2; kk==7 computes a dead tile from mapped pad)
        C0 = __builtin_amdgcn_mfma_f32_32x32x16_f16(aE, bE, zeroC, 0, 0, 0);
        aE = *(const f16x8*)(ap + (i0 + 4) * 32768);   // prefetch ii+4
        bE = *(const f16x8*)(bp + (i0 + 4) * 32768);

        silu_reduce(C1, wp + i0 * 2048 + 2048, phi);
    }

    // combine packed halves, then the two row-halves (lane^32 shares column),
    // apply deferred -ln2 (t = -a*log2e with raw W2)
    float ph = phi.x + phi.y;
    ph += __shfl_xor(ph, 32, 64);
    ph *= -LN2;

    if (lane < 32) {
        atomicAdd(&out[(size_t)(btp * 32 + lane) * 64 + o], ph);
    }
}

extern "C" void kernel_launch(void* const* d_in, const int* in_sizes, int n_in,
                              void* d_out, int out_size, void* d_ws, size_t ws_size,
                              hipStream_t stream) {
    const float* x  = (const float*)d_in[0];
    const float* W1 = (const float*)d_in[1];
    const float* W2 = (const float*)d_in[2];
    const float* B1 = (const float*)d_in[3];
    const float* B2 = (const float*)d_in[4];
    float* out = (float*)d_out;

    // ws: w1img (4MB) | fimg (4MB) | >=256KB pad for tail prefetch over-reads
    f16* w1img = (f16*)d_ws;
    f16* fimg  = w1img + W1IMG_ELEMS;

    prep_kernel<<<832, 256, 0, stream>>>(W1, B1, B2, x, w1img, fimg, out);
    main_kernel<<<NIG * 32 * 64, 128, 0, stream>>>(w1img, fimg, W2, out);
}

// Round 10
// 129.638 us; speedup vs baseline: 1.3110x; 1.3110x over previous
//
#include <hip/hip_runtime.h>
#include <math.h>

typedef _Float16 f16;
typedef f16   f16x8    __attribute__((ext_vector_type(8)));
typedef float floatx2  __attribute__((ext_vector_type(2)));
typedef float floatx4  __attribute__((ext_vector_type(4)));
typedef float floatx16 __attribute__((ext_vector_type(16)));

#define LOG2E 1.44269504088896340736f
#define LN2   0.69314718055994530942f

// Problem constants
#define B_SZ  2048
#define DIN   64
#define DOUT  64
#define NH    32

#define NIG   8                 // i-groups: 16384 blocks -> 4 residency fills
#define IGW   (DIN / NIG)       // 8 i per block

// Images:
//  w1img f16 [i][o][lane(64)][j(8)]: A-frag mfma_32x32x16, m=h=lane&31,
//        k=(lane>>5)*8+j; lanes 32..63 ZERO. Scaled by -log2e; j==7 = B1*(-log2e).
//  fimg  f16 [i][btp(64)][lane(64)][j(8)]: B-frag, n=b=lane&31; j==7 = 1.0.
//        lanes 32..63 never consumed (A zero there) -> not written.
//  W2 read RAW in main ([i][o][h] natively serves the C-layout float4 gather);
//  -ln2 applied once per wave at the end.
#define W1IMG_ELEMS ((size_t)DIN * DOUT * 64 * 8)   // 4 MB
#define FIMG_ELEMS  ((size_t)DIN * 64 * 64 * 8)     // 4 MB

// ---------------------------------------------------------------------------
// prep: bid [0,256)   w1img — 16 (i,o) pairs/block via LDS (coalesced)
//       bid [256,320) fimg  — 1 btp/block, coalesced x via LDS transpose
//       bid [320,832) out[b,o] = sum_i B2[i,o]  (main atomically accumulates)
// ---------------------------------------------------------------------------
__global__ __launch_bounds__(256) void prep_kernel(
        const float* __restrict__ W1, const float* __restrict__ B1,
        const float* __restrict__ B2, const float* __restrict__ x,
        f16* __restrict__ w1img, f16* __restrict__ fimg,
        float* __restrict__ out) {
    const int bid = blockIdx.x, tid = threadIdx.x;
    if (bid < 256) {
        __shared__ float l1[16 * 225];
        __shared__ float lb[16 * 32];
        const int base = bid * 16;       // pair = i*64+o
        for (int g = tid; g < 3584; g += 256) {
            int pair = g / 224, r = g % 224;
            l1[pair * 225 + r] = W1[(size_t)base * 224 + g];
        }
        for (int g = tid; g < 512; g += 256) lb[g] = B1[(size_t)base * 32 + g];
        __syncthreads();
        for (int g = tid; g < 1024; g += 256) {
            int pair = g >> 6, lane = g & 63;
            f16x8 v = {};
            if (lane < 32) {
#pragma unroll
                for (int j = 0; j < 7; ++j)
                    v[j] = (f16)(l1[pair * 225 + lane * 7 + j] * (-LOG2E));
                v[7] = (f16)(lb[pair * 32 + lane] * (-LOG2E));
            }
            *(f16x8*)(w1img + (size_t)bid * 8192 + (size_t)g * 8) = v;
        }
    } else if (bid < 320) {
        __shared__ float ls[32 * 65];
        const int btp = bid - 256;
        for (int g = tid; g < 2048; g += 256) {
            int bb = g >> 6, i = g & 63;
            ls[bb * 65 + i] = x[(size_t)(btp * 32 + bb) * 64 + i];
        }
        __syncthreads();
        for (int g = tid; g < 2048; g += 256) {
            int bb = g & 31, i = g >> 5;
            float xv = ls[bb * 65 + i];
            float s1, c1;
            __sincosf(xv, &s1, &c1);
            float s2 = 2.0f * s1 * c1, c2 = 1.0f - 2.0f * s1 * s1;
            float s4 = 2.0f * s2 * c2, c4 = 1.0f - 2.0f * s2 * s2;
            f16x8 v;
            v[0] = (f16)xv; v[1] = (f16)s1; v[2] = (f16)s2; v[3] = (f16)s4;
            v[4] = (f16)c1; v[5] = (f16)c2; v[6] = (f16)c4; v[7] = (f16)1.0f;
            *(f16x8*)(fimg + ((size_t)(i * 64 + btp) * 64 + bb) * 8) = v;
        }
    } else {
        int e = (bid - 320) * 256 + tid;  // < 131072
        int o = e & 63;
        float s = 0.0f;
#pragma unroll 8
        for (int i = 0; i < 64; ++i) s += B2[i * 64 + o];
        out[e] = s;
    }
}

// ---------------------------------------------------------------------------
// silu+w2 reduce for one C-tile, float2-packed so the backend can form
// v_pk_add/mul/fma_f32 (same algebra as R8's scalar form).
// ---------------------------------------------------------------------------
__device__ __forceinline__ void silu_reduce(const floatx16& C,
                                            const float* __restrict__ wb,
                                            floatx2& phi) {
#pragma unroll
    for (int q = 0; q < 4; ++q) {
        const floatx4 w = *(const floatx4*)(wb + q * 8);
        floatx2 t0 = { C[4 * q + 0], C[4 * q + 1] };
        floatx2 t1 = { C[4 * q + 2], C[4 * q + 3] };
        floatx2 u0 = { __builtin_amdgcn_exp2f(t0.x), __builtin_amdgcn_exp2f(t0.y) };
        floatx2 u1 = { __builtin_amdgcn_exp2f(t1.x), __builtin_amdgcn_exp2f(t1.y) };
        floatx2 v0 = u0 + (floatx2){1.0f, 1.0f};
        floatx2 v1 = u1 + (floatx2){1.0f, 1.0f};
        floatx2 p0 = t0 * (floatx2){w[0], w[1]};
        floatx2 p1 = t1 * (floatx2){w[2], w[3]};
        floatx2 s0 = { __builtin_amdgcn_rcpf(v0.x), __builtin_amdgcn_rcpf(v0.y) };
        floatx2 s1 = { __builtin_amdgcn_rcpf(v1.x), __builtin_amdgcn_rcpf(v1.y) };
        phi = __builtin_elementwise_fma(p0, s0, phi);
        phi = __builtin_elementwise_fma(p1, s1, phi);
    }
}

// ---------------------------------------------------------------------------
// main: grid = 8 ig x 32 og x 64 btp = 16384 blocks, block 128 (2 waves);
// wave w -> o = og*2+w; 8 i per block. R8's proven single-C body (no
// cross-iteration MFMA pipelining — R9 proved dual-C spills). a/b fragments
// prefetched one i ahead. Result atomically added into B2-pre-initialized out.
// ---------------------------------------------------------------------------
__global__ __launch_bounds__(128, 8) void main_kernel(
        const f16* __restrict__ w1img, const f16* __restrict__ fimg,
        const float* __restrict__ W2, float* __restrict__ out) {
    const int tid  = threadIdx.x;
    const int lane = tid & 63;
    const int wv   = tid >> 6;
    const int btp  = blockIdx.x & 63;
    const int og   = (blockIdx.x >> 6) & 31;
    const int ig   = blockIdx.x >> 11;          // 0..7
    const int o    = __builtin_amdgcn_readfirstlane(og * 2 + wv);
    const int p    = lane >> 5;

    const size_t ibase = (size_t)ig * IGW;
    const f16*   ap = w1img + ibase * 32768 + ((size_t)o * 64 + lane) * 8;
    const f16*   bp = fimg  + ibase * 32768 + ((size_t)btp * 64 + lane) * 8;
    const float* wp = W2    + ibase * 2048  + (size_t)o * 32 + p * 4;

    f16x8 a = *(const f16x8*)ap;
    f16x8 b = *(const f16x8*)bp;

    floatx2 phi = {0.0f, 0.0f};
    const floatx16 zeroC = {};

#pragma unroll 1
    for (int ii = 0; ii < IGW; ++ii) {
        const f16x8 ca = a, cb = b;

        // prefetch ii+1 (last iter overruns into the adjacent ws region /
        // end pad — finite garbage, never consumed)
        const size_t i1 = (size_t)(ii + 1);
        a = *(const f16x8*)(ap + i1 * 32768);
        b = *(const f16x8*)(bp + i1 * 32768);

        floatx16 C = __builtin_amdgcn_mfma_f32_32x32x16_f16(ca, cb, zeroC, 0, 0, 0);

        silu_reduce(C, wp + (size_t)ii * 2048, phi);
    }

    // combine packed halves, then the two row-halves (lane^32 shares column),
    // apply deferred -ln2 (t = -a*log2e with raw W2)
    float ph = phi.x + phi.y;
    ph += __shfl_xor(ph, 32, 64);
    ph *= -LN2;

    if (lane < 32) {
        atomicAdd(&out[(size_t)(btp * 32 + lane) * 64 + o], ph);
    }
}

extern "C" void kernel_launch(void* const* d_in, const int* in_sizes, int n_in,
                              void* d_out, int out_size, void* d_ws, size_t ws_size,
                              hipStream_t stream) {
    const float* x  = (const float*)d_in[0];
    const float* W1 = (const float*)d_in[1];
    const float* W2 = (const float*)d_in[2];
    const float* B1 = (const float*)d_in[3];
    const float* B2 = (const float*)d_in[4];
    float* out = (float*)d_out;

    // ws: w1img (4MB) | fimg (4MB) | >=64KB pad for tail prefetch over-reads
    f16* w1img = (f16*)d_ws;
    f16* fimg  = w1img + W1IMG_ELEMS;

    prep_kernel<<<832, 256, 0, stream>>>(W1, B1, B2, x, w1img, fimg, out);
    main_kernel<<<NIG * 32 * 64, 128, 0, stream>>>(w1img, fimg, W2, out);
}